// Round 7
// baseline (516.658 us; speedup 1.0000x reference)
//
#include <hip/hip_runtime.h>

typedef unsigned int uint;
typedef unsigned short ushort;
typedef __attribute__((ext_vector_type(8))) short bf16x8;   // 8 bf16 in 4 VGPRs
typedef __attribute__((ext_vector_type(4))) float f32x4;

namespace {
constexpr int kN = 100000;   // nodes
constexpr int kD = 128;      // feature dim
constexpr int kR = 3;        // relations
constexpr int kE = 500000;   // edges per relation
constexpr int kB = 2;        // bases
constexpr int kRN = kR * kN;              // 300000 segments
constexpr int kRE = kR * kE;              // 1500000 edges
constexpr int kKS = kR * kD;              // stacked K = 384
constexpr int kKC = kD + kKS;             // fused K = 512
constexpr int kNBK = (kN + 511) / 512;    // node buckets per relation (196)
constexpr int kNQ = kR * kNBK;            // relation-buckets (588)
constexpr int kCB = (kRE + 2047) / 2048;  // edge-chunk blocks (733)
constexpr int kBCAP = 4096;               // colbkt capacity (mean 2560, sigma 51 -> 30 sigma)
constexpr int kICAP = 5120;               // colidx capacity incl pad-to-4 (mean ~3320, 28 sigma)
}

__device__ __forceinline__ ushort f2bf(float f) {
    uint u = __builtin_bit_cast(uint, f);
    u += 0x7fff + ((u >> 16) & 1);           // RNE
    return (ushort)(u >> 16);
}
__device__ __forceinline__ float bf2f(ushort h) {
    return __builtin_bit_cast(float, (uint)h << 16);
}
__device__ __forceinline__ int rel_of(int i) {
    return (i >= kE) + (i >= 2 * kE);
}

// ---------------- init: bucket cursors at fixed slot bases ----------------
__global__ __launch_bounds__(256)
void init_kernel(unsigned* __restrict__ bcur)
{
    const int q = blockIdx.x * 256 + threadIdx.x;
    if (q < kNQ) bcur[q] = (unsigned)q * kBCAP;
}

// ---------------- passB: bin edges into fixed bucket slots ----------------
// record = (src << 9) | (dst & 511); bucket q = r*kNBK + (dst>>9)
__global__ __launch_bounds__(256)
void passB_kernel(const int* __restrict__ src, const int* __restrict__ dst,
                  unsigned* __restrict__ bcur, uint* __restrict__ colbkt)
{
    __shared__ unsigned bl[kNQ];     // local counts, then local cursors
    __shared__ unsigned base_l[kNQ];
    const int tid = threadIdx.x;
    for (int q = tid; q < kNQ; q += 256) bl[q] = 0;
    __syncthreads();
    const int i0 = blockIdx.x * 2048 + tid * 8;
    int dd[8], qq[8];
    const bool full = (i0 + 8 <= kRE);
    if (full) {
        const int4 d0 = *(const int4*)(dst + i0);
        const int4 d1 = *(const int4*)(dst + i0 + 4);
        dd[0]=d0.x; dd[1]=d0.y; dd[2]=d0.z; dd[3]=d0.w;
        dd[4]=d1.x; dd[5]=d1.y; dd[6]=d1.z; dd[7]=d1.w;
        #pragma unroll
        for (int j = 0; j < 8; ++j) {
            qq[j] = rel_of(i0 + j) * kNBK + (dd[j] >> 9);
            atomicAdd(&bl[qq[j]], 1u);
        }
    } else {
        for (int j = 0; j < 8; ++j) {
            const int i = i0 + j;
            qq[j] = -1;
            if (i < kRE) {
                dd[j] = dst[i];
                qq[j] = rel_of(i) * kNBK + (dd[j] >> 9);
                atomicAdd(&bl[qq[j]], 1u);
            }
        }
    }
    __syncthreads();
    for (int q = tid; q < kNQ; q += 256) {
        const unsigned c = bl[q];
        base_l[q] = c ? atomicAdd(&bcur[q], c) : 0u;
        bl[q] = 0;   // reuse as local cursor
    }
    __syncthreads();
    if (full) {
        const int4 s0 = *(const int4*)(src + i0);
        const int4 s1 = *(const int4*)(src + i0 + 4);
        const int ss[8] = {s0.x, s0.y, s0.z, s0.w, s1.x, s1.y, s1.z, s1.w};
        #pragma unroll
        for (int j = 0; j < 8; ++j) {
            const unsigned pos = base_l[qq[j]] + atomicAdd(&bl[qq[j]], 1u);
            colbkt[pos] = ((uint)ss[j] << 9) | (uint)(dd[j] & 511);
        }
    } else {
        for (int j = 0; j < 8; ++j) {
            if (qq[j] >= 0) {
                const unsigned pos = base_l[qq[j]] + atomicAdd(&bl[qq[j]], 1u);
                colbkt[pos] = ((uint)src[i0 + j] << 9) | (uint)(dd[j] & 511);
            }
        }
    }
}

// ---------------- passC: per-bucket count + LDS scan (padded to x4) -> rowseg/invd/colidx ----------------
__global__ __launch_bounds__(256)
void passC_kernel(const uint* __restrict__ colbkt, const unsigned* __restrict__ bcur,
                  uint2* __restrict__ rowseg, float* __restrict__ invd,
                  int* __restrict__ colidx)
{
    __shared__ unsigned cnt[512];
    __shared__ unsigned pos[512];
    __shared__ unsigned psc[256];
    const int tid = threadIdx.x;
    const int q = blockIdx.x;            // 0..kNQ-1
    const int r = q / kNBK;
    const int b = q - r * kNBK;
    const int n0 = b << 9;
    const int nn = min(512, kN - n0);
    cnt[tid] = 0; cnt[tid + 256] = 0;
    __syncthreads();
    const unsigned e0 = (unsigned)q * kBCAP;
    const unsigned e1 = bcur[q];
    for (unsigned j = e0 + tid; j < e1; j += 256)
        atomicAdd(&cnt[colbkt[j] & 511u], 1u);
    __syncthreads();
    // padded (x4) sizes; exclusive scan of 512 padded counts
    const unsigned c0 = cnt[2 * tid], c1 = cnt[2 * tid + 1];
    const unsigned c0p = (c0 + 3u) & ~3u, c1p = (c1 + 3u) & ~3u;
    const unsigned psum = c0p + c1p;
    psc[tid] = psum;
    __syncthreads();
    #pragma unroll
    for (int off = 1; off < 256; off <<= 1) {
        unsigned t = (tid >= off) ? psc[tid - off] : 0u;
        __syncthreads();
        psc[tid] += t;
        __syncthreads();
    }
    const unsigned pex = psc[tid] - psum;                 // exclusive prefix (padded)
    const unsigned beg0 = (unsigned)q * kICAP + pex;
    const unsigned beg1 = beg0 + c0p;
    pos[2 * tid] = beg0;
    pos[2 * tid + 1] = beg1;
    const int g0 = 2 * tid, g1 = 2 * tid + 1;
    if (g0 < nn) {
        rowseg[(size_t)r * kN + n0 + g0] = make_uint2(beg0, beg0 + c0p);
        invd[(size_t)r * kN + n0 + g0] = 1.0f / (float)(c0 > 1u ? c0 : 1u);
        for (unsigned u = c0; u < c0p; ++u) colidx[beg0 + u] = kN;   // pad -> zero row
    }
    if (g1 < nn) {
        rowseg[(size_t)r * kN + n0 + g1] = make_uint2(beg1, beg1 + c1p);
        invd[(size_t)r * kN + n0 + g1] = 1.0f / (float)(c1 > 1u ? c1 : 1u);
        for (unsigned u = c1; u < c1p; ++u) colidx[beg1 + u] = kN;
    }
    __syncthreads();
    // scatter into slotted colidx
    for (unsigned j = e0 + tid; j < e1; j += 256) {
        const uint p = colbkt[j];
        const unsigned pp = atomicAdd(&pos[p & 511u], 1u);
        colidx[pp] = (int)(p >> 9);
    }
}

// ---------------- fused weight prep + zero rows ----------------
// blocks [0,64): WTp = proj_w^T; [64,320): WTc1; [320,576): WTc2; 576/577: zero rows
__device__ __forceinline__ void wcomb_one(int i, const float* loopW, const float* basis,
                                          const float* coeff, ushort* WTc)
{
    int out = i >> 9;
    int k = i & (kKC - 1);
    float v;
    if (k < kD) {
        v = loopW[(size_t)k * kD + out];
    } else {
        int j = k - kD;
        int r = j >> 7, d = j & 127;
        v = coeff[r * kB] * basis[(size_t)d * kD + out]
          + coeff[r * kB + 1] * basis[(size_t)kD * kD + d * kD + out];
    }
    WTc[i] = f2bf(v);
}

__global__ __launch_bounds__(256)
void prep_kernel(const float* __restrict__ proj_w,
                 const float* __restrict__ loop1, const float* __restrict__ basis1,
                 const float* __restrict__ coeff1,
                 const float* __restrict__ loop2, const float* __restrict__ basis2,
                 const float* __restrict__ coeff2,
                 ushort* __restrict__ WTp, ushort* __restrict__ WTc1,
                 ushort* __restrict__ WTc2,
                 ushort* __restrict__ hbZero, ushort* __restrict__ r1bZero)
{
    const int b = blockIdx.x;
    const int tid = threadIdx.x;
    if (b < 64) {
        const int i = b * 256 + tid;           // 16384
        const int out = i >> 7, k = i & 127;
        WTp[i] = f2bf(proj_w[(size_t)k * kD + out]);
    } else if (b < 320) {
        wcomb_one((b - 64) * 256 + tid, loop1, basis1, coeff1, WTc1);
    } else if (b < 576) {
        wcomb_one((b - 320) * 256 + tid, loop2, basis2, coeff2, WTc2);
    } else if (b == 576) {
        if (tid < kD) hbZero[tid] = 0;
    } else {
        if (tid < kD) r1bZero[tid] = 0;
    }
}

// ---------------- gather: a[n, r*128+c] = invdeg[r,n] * sum in[src, c] ----------------
// 8-lane groups, one segment per group (32 segs/block); 32B/lane.
// Segments are padded to multiples of 4 edges (pad entries -> zero row kN):
// pure unroll-4 loop, 1 int4 colidx load + 8 row loads in flight per iteration.
__device__ __forceinline__ void acc8(float* s, uint4 v) {
    s[0] += bf2f((ushort)(v.x & 0xffffu)); s[1] += bf2f((ushort)(v.x >> 16));
    s[2] += bf2f((ushort)(v.y & 0xffffu)); s[3] += bf2f((ushort)(v.y >> 16));
    s[4] += bf2f((ushort)(v.z & 0xffffu)); s[5] += bf2f((ushort)(v.z >> 16));
    s[6] += bf2f((ushort)(v.w & 0xffffu)); s[7] += bf2f((ushort)(v.w >> 16));
}

__global__ __launch_bounds__(256)
void gather_kernel(const ushort* __restrict__ in, const uint2* __restrict__ rowseg,
                   const int* __restrict__ colidx, const float* __restrict__ invd,
                   ushort* __restrict__ a)
{
    const int tid = threadIdx.x;
    const int g   = tid >> 3;            // 0..31: segment slot
    const int c   = tid & 7;             // 32B column chunk (16 bf16)
    const int seg = blockIdx.x * 32 + g; // grid exact: 9375*32 = 300000
    const int r = seg / kN;
    const int n = seg - r * kN;
    const uint2 be = rowseg[seg];

    float s[16];
    #pragma unroll
    for (int i = 0; i < 16; ++i) s[i] = 0.f;

    for (unsigned j = be.x; j < be.y; j += 4) {
        const int4 e = *(const int4*)(colidx + j);    // 16B-aligned (padded slots)
        const ushort* p0 = in + (size_t)e.x * kD + c * 16;
        const ushort* p1 = in + (size_t)e.y * kD + c * 16;
        const ushort* p2 = in + (size_t)e.z * kD + c * 16;
        const ushort* p3 = in + (size_t)e.w * kD + c * 16;
        const uint4 v00 = *(const uint4*)p0;
        const uint4 v01 = *(const uint4*)(p0 + 8);
        const uint4 v10 = *(const uint4*)p1;
        const uint4 v11 = *(const uint4*)(p1 + 8);
        const uint4 v20 = *(const uint4*)p2;
        const uint4 v21 = *(const uint4*)(p2 + 8);
        const uint4 v30 = *(const uint4*)p3;
        const uint4 v31 = *(const uint4*)(p3 + 8);
        acc8(s, v00); acc8(s + 8, v01);
        acc8(s, v10); acc8(s + 8, v11);
        acc8(s, v20); acc8(s + 8, v21);
        acc8(s, v30); acc8(s + 8, v31);
    }

    const float w = invd[seg];
    uint4 o0, o1;
    o0.x = (uint)f2bf(s[0] * w)  | ((uint)f2bf(s[1] * w)  << 16);
    o0.y = (uint)f2bf(s[2] * w)  | ((uint)f2bf(s[3] * w)  << 16);
    o0.z = (uint)f2bf(s[4] * w)  | ((uint)f2bf(s[5] * w)  << 16);
    o0.w = (uint)f2bf(s[6] * w)  | ((uint)f2bf(s[7] * w)  << 16);
    o1.x = (uint)f2bf(s[8] * w)  | ((uint)f2bf(s[9] * w)  << 16);
    o1.y = (uint)f2bf(s[10] * w) | ((uint)f2bf(s[11] * w) << 16);
    o1.z = (uint)f2bf(s[12] * w) | ((uint)f2bf(s[13] * w) << 16);
    o1.w = (uint)f2bf(s[14] * w) | ((uint)f2bf(s[15] * w) << 16);
    ushort* ap = a + (size_t)n * kKS + r * kD + c * 16;
    *(uint4*)ap       = o0;
    *(uint4*)(ap + 8) = o1;
}

// ---------------- MFMA GEMM (BM=64): C[M,128] = [A0 | A1][M,NT*64] @ WT^T (+bias) ----------------
// A0: first NT0 64-chunks (fp32 if AFP32, else bf16; row stride NT0*64);
// A1: remaining chunks (bf16, row stride (NT-NT0)*64).
// WT: [128][NT*64] pre-transposed bf16. 256 thr, 4 waves 2x2 of 32x64.
// LDS: As[64][64], Bs[128][64] bf16, XOR-swizzled (16B chunk index ^= row&7), linear ds_write.
// BM=64 -> 1563 blocks: ~6 blocks/CU (24KB LDS) for latency hiding.
template<int NT0, int NT, bool AFP32, bool RELUOUT, bool OUTBF16>
__global__ __launch_bounds__(256)
void mfma_gemm(const void* __restrict__ A0, const ushort* __restrict__ A1,
               const ushort* __restrict__ WT, const float* __restrict__ bias,
               void* __restrict__ Cout, int M)
{
    __shared__ ushort As[64 * 64];
    __shared__ ushort Bs[128 * 64];
    const int tid  = threadIdx.x;
    const int bm   = blockIdx.x * 64;
    const int lane = tid & 63;
    const int w    = tid >> 6;
    const int wrow = (w >> 1) * 32;
    const int wcol = (w & 1) * 64;

    f32x4 acc[2][4];
    #pragma unroll
    for (int i = 0; i < 2; ++i)
        #pragma unroll
        for (int j = 0; j < 4; ++j)
            acc[i][j] = (f32x4){0.f, 0.f, 0.f, 0.f};

    uint4 a4[2], b4[4];

    auto load_tile = [&](int kt) {
        #pragma unroll
        for (int st = 0; st < 2; ++st) {
            const int m = st * 256 + tid;
            const int row = m >> 3;
            const int osrc = (m & 7) ^ (row & 7);
            int arow = bm + row; if (arow >= M) arow = M - 1;   // clamp: rows>=M unused
            if (kt < NT0) {
                if (AFP32) {
                    const float* ap = (const float*)A0 + (size_t)arow * (NT0 * 64) + kt * 64 + osrc * 8;
                    const float4 f0 = *(const float4*)ap;
                    const float4 f1 = *(const float4*)(ap + 4);
                    a4[st].x = (uint)f2bf(f0.x) | ((uint)f2bf(f0.y) << 16);
                    a4[st].y = (uint)f2bf(f0.z) | ((uint)f2bf(f0.w) << 16);
                    a4[st].z = (uint)f2bf(f1.x) | ((uint)f2bf(f1.y) << 16);
                    a4[st].w = (uint)f2bf(f1.z) | ((uint)f2bf(f1.w) << 16);
                } else {
                    a4[st] = *(const uint4*)((const ushort*)A0 + (size_t)arow * (NT0 * 64) + kt * 64 + osrc * 8);
                }
            } else {
                a4[st] = *(const uint4*)(A1 + (size_t)arow * ((NT - NT0) * 64) + (kt - NT0) * 64 + osrc * 8);
            }
        }
        #pragma unroll
        for (int st = 0; st < 4; ++st) {
            const int m = st * 256 + tid;
            const int row = m >> 3;
            const int osrc = (m & 7) ^ (row & 7);
            b4[st] = *(const uint4*)(WT + (size_t)row * (NT * 64) + kt * 64 + osrc * 8);
        }
    };

    load_tile(0);
    #pragma unroll
    for (int kt = 0; kt < NT; ++kt) {
        __syncthreads();
        #pragma unroll
        for (int st = 0; st < 2; ++st) {
            const int m = st * 256 + tid;
            *(uint4*)&As[m * 8] = a4[st];
        }
        #pragma unroll
        for (int st = 0; st < 4; ++st) {
            const int m = st * 256 + tid;
            *(uint4*)&Bs[m * 8] = b4[st];
        }
        __syncthreads();
        if (kt + 1 < NT) load_tile(kt + 1);   // prefetch under MFMA

        #pragma unroll
        for (int ks = 0; ks < 2; ++ks) {
            const int oq = ks * 4 + (lane >> 4);
            bf16x8 af[2], bfr[4];
            #pragma unroll
            for (int am = 0; am < 2; ++am) {
                const int row = wrow + am * 16 + (lane & 15);
                const int oL = oq ^ (row & 7);
                af[am] = *(const bf16x8*)&As[row * 64 + oL * 8];
            }
            #pragma unroll
            for (int bn = 0; bn < 4; ++bn) {
                const int row = wcol + bn * 16 + (lane & 15);
                const int oL = oq ^ (row & 7);
                bfr[bn] = *(const bf16x8*)&Bs[row * 64 + oL * 8];
            }
            #pragma unroll
            for (int am = 0; am < 2; ++am)
                #pragma unroll
                for (int bn = 0; bn < 4; ++bn)
                    acc[am][bn] = __builtin_amdgcn_mfma_f32_16x16x32_bf16(
                        af[am], bfr[bn], acc[am][bn], 0, 0, 0);
        }
    }

    // epilogue: row = bm+wrow+am*16+4*(lane>>4)+r ; col = wcol+bn*16+(lane&15)
    const int ccol = wcol + (lane & 15);
    float bb[4];
    #pragma unroll
    for (int bn = 0; bn < 4; ++bn) bb[bn] = bias[ccol + bn * 16];

    const int crow0 = bm + wrow + 4 * (lane >> 4);
    #pragma unroll
    for (int am = 0; am < 2; ++am) {
        #pragma unroll
        for (int r = 0; r < 4; ++r) {
            const int row = crow0 + am * 16 + r;
            if (row < M) {
                #pragma unroll
                for (int bn = 0; bn < 4; ++bn) {
                    float v = acc[am][bn][r] + bb[bn];
                    if (RELUOUT) v = fmaxf(v, 0.f);
                    if (OUTBF16)
                        ((ushort*)Cout)[(size_t)row * kD + ccol + bn * 16] = f2bf(v);
                    else
                        ((float*)Cout)[(size_t)row * kD + ccol + bn * 16] = v;
                }
            }
        }
    }
}

extern "C" void kernel_launch(void* const* d_in, const int* in_sizes, int n_in,
                              void* d_out, int out_size, void* d_ws, size_t ws_size,
                              hipStream_t stream)
{
    const float* x      = (const float*)d_in[0];
    const int*   esrc   = (const int*)d_in[1];
    const int*   edst   = (const int*)d_in[2];
    const float* proj_w = (const float*)d_in[3];
    const float* proj_b = (const float*)d_in[4];
    const float* basis1 = (const float*)d_in[5];
    const float* coeff1 = (const float*)d_in[6];
    const float* bias1  = (const float*)d_in[7];
    const float* loop1  = (const float*)d_in[8];
    const float* basis2 = (const float*)d_in[9];
    const float* coeff2 = (const float*)d_in[10];
    const float* bias2  = (const float*)d_in[11];
    const float* loop2  = (const float*)d_in[12];

    // ---- workspace layout ----
    char* p = (char*)d_ws;
    ushort* hb    = (ushort*)p;  p += (size_t)(kN + 1) * kD * 2;  // bf16 h (+ zero row kN)
    ushort* r1b   = (ushort*)p;  p += (size_t)(kN + 1) * kD * 2;  // bf16 relu(layer1) (+ zero row)
    ushort* ab    = (ushort*)p;  p += (size_t)kN * kKS * 2;       // bf16 gathered [N,384]
    ushort* WTp   = (ushort*)p;  p += (size_t)kD * kD * 2;        // proj_w^T
    ushort* WTc1  = (ushort*)p;  p += (size_t)kD * kKC * 2;       // [loop1 | Wstk1]^T
    ushort* WTc2  = (ushort*)p;  p += (size_t)kD * kKC * 2;       // [loop2 | Wstk2]^T
    float* invd   = (float*)p;   p += (size_t)kRN * 4;
    uint2* rowseg = (uint2*)p;   p += (size_t)kRN * 8;
    unsigned* bcur = (unsigned*)p;  p += (size_t)kNQ * 4;
    uint* colbkt   = (uint*)p;      p += (size_t)kNQ * kBCAP * 4;
    int* colidx    = (int*)p;       p += (size_t)kNQ * kICAP * 4;

    // ---- CSR build: fixed bucket slots, no global count/scan ----
    init_kernel<<<(kNQ + 255) / 256, 256, 0, stream>>>(bcur);
    passB_kernel<<<kCB, 256, 0, stream>>>(esrc, edst, bcur, colbkt);
    passC_kernel<<<kNQ, 256, 0, stream>>>(colbkt, bcur, rowseg, invd, colidx);

    // ---- fused weight prep + zero rows ----
    prep_kernel<<<578, 256, 0, stream>>>(proj_w, loop1, basis1, coeff1,
                                         loop2, basis2, coeff2, WTp, WTc1, WTc2,
                                         hb + (size_t)kN * kD, r1b + (size_t)kN * kD);

    const int gblocks = (kN + 63) / 64;     // 1563
    const int gatherblocks = kRN / 32;      // 9375 exact

    // ---- projection: hb = bf16(x @ proj_w + proj_b), fp32 A read in-GEMM ----
    mfma_gemm<2, 2, true, false, true><<<gblocks, 256, 0, stream>>>(
        x, nullptr, WTp, proj_b, hb, kN);

    // ---- layer 1: r1b = bf16(relu([h | gather(h)] @ [loop1|Wstk1] + bias1)) ----
    gather_kernel<<<gatherblocks, 256, 0, stream>>>(hb, rowseg, colidx, invd, ab);
    mfma_gemm<2, 8, false, true, true><<<gblocks, 256, 0, stream>>>(
        hb, ab, WTc1, bias1, r1b, kN);

    // ---- layer 2: out = relu([r1 | gather(r1)] @ [loop2|Wstk2] + bias2) (fp32) ----
    gather_kernel<<<gatherblocks, 256, 0, stream>>>(r1b, rowseg, colidx, invd, ab);
    mfma_gemm<2, 8, false, true, false><<<gblocks, 256, 0, stream>>>(
        r1b, ab, WTc2, bias2, d_out, kN);
}

// Round 8
// 356.965 us; speedup vs baseline: 1.4474x; 1.4474x over previous
//
#include <hip/hip_runtime.h>

typedef unsigned int uint;
typedef unsigned short ushort;
typedef __attribute__((ext_vector_type(8))) short bf16x8;   // 8 bf16 in 4 VGPRs
typedef __attribute__((ext_vector_type(4))) float f32x4;

namespace {
constexpr int kN = 100000;   // nodes
constexpr int kD = 128;      // feature dim
constexpr int kR = 3;        // relations
constexpr int kE = 500000;   // edges per relation
constexpr int kB = 2;        // bases
constexpr int kRN = kR * kN;              // 300000 segments
constexpr int kRE = kR * kE;              // 1500000 edges
constexpr int kKS = kR * kD;              // stacked K = 384
constexpr int kKC = kD + kKS;             // fused K = 512
constexpr int kNBK = (kN + 511) / 512;    // node buckets per relation (196)
constexpr int kNQ = kR * kNBK;            // relation-buckets (588)
constexpr int kCB = (kRE + 2047) / 2048;  // edge-chunk blocks (733)
constexpr int kBCAP = 4096;               // colbkt capacity (mean 2560, sigma 51 -> 30 sigma)
constexpr int kICAP = 5120;               // colidx capacity incl pad-to-4 (mean ~3320, 28 sigma)
}

__device__ __forceinline__ ushort f2bf(float f) {
    uint u = __builtin_bit_cast(uint, f);
    u += 0x7fff + ((u >> 16) & 1);           // RNE
    return (ushort)(u >> 16);
}
__device__ __forceinline__ float bf2f(ushort h) {
    return __builtin_bit_cast(float, (uint)h << 16);
}
__device__ __forceinline__ int rel_of(int i) {
    return (i >= kE) + (i >= 2 * kE);
}

// async global->LDS DMA, 16B per lane; LDS dest must be wave-uniform base (lane*16 added by HW)
__device__ __forceinline__ void gload16(const void* g, void* l) {
    __builtin_amdgcn_global_load_lds(
        (__attribute__((address_space(1))) void*)(g),
        (__attribute__((address_space(3))) void*)(l),
        16, 0, 0);
}

// ---------------- init: bucket cursors at fixed slot bases ----------------
__global__ __launch_bounds__(256)
void init_kernel(unsigned* __restrict__ bcur)
{
    const int q = blockIdx.x * 256 + threadIdx.x;
    if (q < kNQ) bcur[q] = (unsigned)q * kBCAP;
}

// ---------------- x -> bf16 ----------------
__global__ __launch_bounds__(256)
void f2bf_kernel(const float* __restrict__ in, ushort* __restrict__ out)
{
    const int i = blockIdx.x * 256 + threadIdx.x;   // over N*D/4 exactly
    const float4 v = ((const float4*)in)[i];
    ushort4 o;
    o.x = f2bf(v.x); o.y = f2bf(v.y); o.z = f2bf(v.z); o.w = f2bf(v.w);
    ((ushort4*)out)[i] = o;
}

// ---------------- passB: bin edges into fixed bucket slots ----------------
// record = (src << 9) | (dst & 511); bucket q = r*kNBK + (dst>>9)
__global__ __launch_bounds__(256)
void passB_kernel(const int* __restrict__ src, const int* __restrict__ dst,
                  unsigned* __restrict__ bcur, uint* __restrict__ colbkt)
{
    __shared__ unsigned bl[kNQ];     // local counts, then local cursors
    __shared__ unsigned base_l[kNQ];
    const int tid = threadIdx.x;
    for (int q = tid; q < kNQ; q += 256) bl[q] = 0;
    __syncthreads();
    const int i0 = blockIdx.x * 2048 + tid * 8;
    int dd[8], qq[8];
    const bool full = (i0 + 8 <= kRE);
    if (full) {
        const int4 d0 = *(const int4*)(dst + i0);
        const int4 d1 = *(const int4*)(dst + i0 + 4);
        dd[0]=d0.x; dd[1]=d0.y; dd[2]=d0.z; dd[3]=d0.w;
        dd[4]=d1.x; dd[5]=d1.y; dd[6]=d1.z; dd[7]=d1.w;
        #pragma unroll
        for (int j = 0; j < 8; ++j) {
            qq[j] = rel_of(i0 + j) * kNBK + (dd[j] >> 9);
            atomicAdd(&bl[qq[j]], 1u);
        }
    } else {
        for (int j = 0; j < 8; ++j) {
            const int i = i0 + j;
            qq[j] = -1;
            if (i < kRE) {
                dd[j] = dst[i];
                qq[j] = rel_of(i) * kNBK + (dd[j] >> 9);
                atomicAdd(&bl[qq[j]], 1u);
            }
        }
    }
    __syncthreads();
    for (int q = tid; q < kNQ; q += 256) {
        const unsigned c = bl[q];
        base_l[q] = c ? atomicAdd(&bcur[q], c) : 0u;
        bl[q] = 0;   // reuse as local cursor
    }
    __syncthreads();
    if (full) {
        const int4 s0 = *(const int4*)(src + i0);
        const int4 s1 = *(const int4*)(src + i0 + 4);
        const int ss[8] = {s0.x, s0.y, s0.z, s0.w, s1.x, s1.y, s1.z, s1.w};
        #pragma unroll
        for (int j = 0; j < 8; ++j) {
            const unsigned pos = base_l[qq[j]] + atomicAdd(&bl[qq[j]], 1u);
            colbkt[pos] = ((uint)ss[j] << 9) | (uint)(dd[j] & 511);
        }
    } else {
        for (int j = 0; j < 8; ++j) {
            if (qq[j] >= 0) {
                const unsigned pos = base_l[qq[j]] + atomicAdd(&bl[qq[j]], 1u);
                colbkt[pos] = ((uint)src[i0 + j] << 9) | (uint)(dd[j] & 511);
            }
        }
    }
}

// ---------------- passC: per-bucket count + LDS scan (padded to x4) -> rowseg/invd/colidx ----------------
__global__ __launch_bounds__(256)
void passC_kernel(const uint* __restrict__ colbkt, const unsigned* __restrict__ bcur,
                  uint2* __restrict__ rowseg, float* __restrict__ invd,
                  int* __restrict__ colidx)
{
    __shared__ unsigned cnt[512];
    __shared__ unsigned pos[512];
    __shared__ unsigned psc[256];
    const int tid = threadIdx.x;
    const int q = blockIdx.x;            // 0..kNQ-1
    const int r = q / kNBK;
    const int b = q - r * kNBK;
    const int n0 = b << 9;
    const int nn = min(512, kN - n0);
    cnt[tid] = 0; cnt[tid + 256] = 0;
    __syncthreads();
    const unsigned e0 = (unsigned)q * kBCAP;
    const unsigned e1 = bcur[q];
    for (unsigned j = e0 + tid; j < e1; j += 256)
        atomicAdd(&cnt[colbkt[j] & 511u], 1u);
    __syncthreads();
    // padded (x4) sizes; exclusive scan of 512 padded counts
    const unsigned c0 = cnt[2 * tid], c1 = cnt[2 * tid + 1];
    const unsigned c0p = (c0 + 3u) & ~3u, c1p = (c1 + 3u) & ~3u;
    const unsigned psum = c0p + c1p;
    psc[tid] = psum;
    __syncthreads();
    #pragma unroll
    for (int off = 1; off < 256; off <<= 1) {
        unsigned t = (tid >= off) ? psc[tid - off] : 0u;
        __syncthreads();
        psc[tid] += t;
        __syncthreads();
    }
    const unsigned pex = psc[tid] - psum;                 // exclusive prefix (padded)
    const unsigned beg0 = (unsigned)q * kICAP + pex;
    const unsigned beg1 = beg0 + c0p;
    pos[2 * tid] = beg0;
    pos[2 * tid + 1] = beg1;
    const int g0 = 2 * tid, g1 = 2 * tid + 1;
    if (g0 < nn) {
        rowseg[(size_t)r * kN + n0 + g0] = make_uint2(beg0, beg0 + c0p);
        invd[(size_t)r * kN + n0 + g0] = 1.0f / (float)(c0 > 1u ? c0 : 1u);
        for (unsigned u = c0; u < c0p; ++u) colidx[beg0 + u] = kN;   // pad -> zero row
    }
    if (g1 < nn) {
        rowseg[(size_t)r * kN + n0 + g1] = make_uint2(beg1, beg1 + c1p);
        invd[(size_t)r * kN + n0 + g1] = 1.0f / (float)(c1 > 1u ? c1 : 1u);
        for (unsigned u = c1; u < c1p; ++u) colidx[beg1 + u] = kN;
    }
    __syncthreads();
    // scatter into slotted colidx
    for (unsigned j = e0 + tid; j < e1; j += 256) {
        const uint p = colbkt[j];
        const unsigned pp = atomicAdd(&pos[p & 511u], 1u);
        colidx[pp] = (int)(p >> 9);
    }
}

// ---------------- fused weight prep + zero rows ----------------
// blocks [0,64): WTp = proj_w^T; [64,320): WTc1; [320,576): WTc2; 576/577: zero rows
__device__ __forceinline__ void wcomb_one(int i, const float* loopW, const float* basis,
                                          const float* coeff, ushort* WTc)
{
    int out = i >> 9;
    int k = i & (kKC - 1);
    float v;
    if (k < kD) {
        v = loopW[(size_t)k * kD + out];
    } else {
        int j = k - kD;
        int r = j >> 7, d = j & 127;
        v = coeff[r * kB] * basis[(size_t)d * kD + out]
          + coeff[r * kB + 1] * basis[(size_t)kD * kD + d * kD + out];
    }
    WTc[i] = f2bf(v);
}

__global__ __launch_bounds__(256)
void prep_kernel(const float* __restrict__ proj_w,
                 const float* __restrict__ loop1, const float* __restrict__ basis1,
                 const float* __restrict__ coeff1,
                 const float* __restrict__ loop2, const float* __restrict__ basis2,
                 const float* __restrict__ coeff2,
                 ushort* __restrict__ WTp, ushort* __restrict__ WTc1,
                 ushort* __restrict__ WTc2,
                 ushort* __restrict__ hbZero, ushort* __restrict__ r1bZero)
{
    const int b = blockIdx.x;
    const int tid = threadIdx.x;
    if (b < 64) {
        const int i = b * 256 + tid;           // 16384
        const int out = i >> 7, k = i & 127;
        WTp[i] = f2bf(proj_w[(size_t)k * kD + out]);
    } else if (b < 320) {
        wcomb_one((b - 64) * 256 + tid, loop1, basis1, coeff1, WTc1);
    } else if (b < 576) {
        wcomb_one((b - 320) * 256 + tid, loop2, basis2, coeff2, WTc2);
    } else if (b == 576) {
        if (tid < kD) hbZero[tid] = 0;
    } else {
        if (tid < kD) r1bZero[tid] = 0;
    }
}

// ---------------- gather: a[n, r*128+c] = invdeg[r,n] * sum in[src, c] ----------------
// 8-lane groups, one segment per group (32 segs/block); 32B/lane.
// Segments padded to x4 edges (pads -> zero row kN): pure unroll-4, 8 row loads in flight.
__device__ __forceinline__ void acc8(float* s, uint4 v) {
    s[0] += bf2f((ushort)(v.x & 0xffffu)); s[1] += bf2f((ushort)(v.x >> 16));
    s[2] += bf2f((ushort)(v.y & 0xffffu)); s[3] += bf2f((ushort)(v.y >> 16));
    s[4] += bf2f((ushort)(v.z & 0xffffu)); s[5] += bf2f((ushort)(v.z >> 16));
    s[6] += bf2f((ushort)(v.w & 0xffffu)); s[7] += bf2f((ushort)(v.w >> 16));
}

__global__ __launch_bounds__(256)
void gather_kernel(const ushort* __restrict__ in, const uint2* __restrict__ rowseg,
                   const int* __restrict__ colidx, const float* __restrict__ invd,
                   ushort* __restrict__ a)
{
    const int tid = threadIdx.x;
    const int g   = tid >> 3;            // 0..31: segment slot
    const int c   = tid & 7;             // 32B column chunk (16 bf16)
    const int seg = blockIdx.x * 32 + g; // grid exact: 9375*32 = 300000
    const int r = seg / kN;
    const int n = seg - r * kN;
    const uint2 be = rowseg[seg];

    float s[16];
    #pragma unroll
    for (int i = 0; i < 16; ++i) s[i] = 0.f;

    for (unsigned j = be.x; j < be.y; j += 4) {
        const int4 e = *(const int4*)(colidx + j);    // 16B-aligned (padded slots)
        const ushort* p0 = in + (size_t)e.x * kD + c * 16;
        const ushort* p1 = in + (size_t)e.y * kD + c * 16;
        const ushort* p2 = in + (size_t)e.z * kD + c * 16;
        const ushort* p3 = in + (size_t)e.w * kD + c * 16;
        const uint4 v00 = *(const uint4*)p0;
        const uint4 v01 = *(const uint4*)(p0 + 8);
        const uint4 v10 = *(const uint4*)p1;
        const uint4 v11 = *(const uint4*)(p1 + 8);
        const uint4 v20 = *(const uint4*)p2;
        const uint4 v21 = *(const uint4*)(p2 + 8);
        const uint4 v30 = *(const uint4*)p3;
        const uint4 v31 = *(const uint4*)(p3 + 8);
        acc8(s, v00); acc8(s + 8, v01);
        acc8(s, v10); acc8(s + 8, v11);
        acc8(s, v20); acc8(s + 8, v21);
        acc8(s, v30); acc8(s + 8, v31);
    }

    const float w = invd[seg];
    uint4 o0, o1;
    o0.x = (uint)f2bf(s[0] * w)  | ((uint)f2bf(s[1] * w)  << 16);
    o0.y = (uint)f2bf(s[2] * w)  | ((uint)f2bf(s[3] * w)  << 16);
    o0.z = (uint)f2bf(s[4] * w)  | ((uint)f2bf(s[5] * w)  << 16);
    o0.w = (uint)f2bf(s[6] * w)  | ((uint)f2bf(s[7] * w)  << 16);
    o1.x = (uint)f2bf(s[8] * w)  | ((uint)f2bf(s[9] * w)  << 16);
    o1.y = (uint)f2bf(s[10] * w) | ((uint)f2bf(s[11] * w) << 16);
    o1.z = (uint)f2bf(s[12] * w) | ((uint)f2bf(s[13] * w) << 16);
    o1.w = (uint)f2bf(s[14] * w) | ((uint)f2bf(s[15] * w) << 16);
    ushort* ap = a + (size_t)n * kKS + r * kD + c * 16;
    *(uint4*)ap       = o0;
    *(uint4*)(ap + 8) = o1;
}

// ---------------- MFMA GEMM (BM=128, global_load_lds, LDS double-buffer) ----------------
// C[M,128] = [A0 | A1][M,NT*64] @ WT^T (+bias). A0 row stride NT0*64, A1 stride (NT-NT0)*64,
// all bf16. WT: [128][NT*64] pre-transposed bf16. 256 thr, 4 waves 2x2 of 64x64.
// LDS tiles [128][64] bf16, XOR-swizzled via pre-swizzled GLOBAL source (dest linear),
// staged with 16B global_load_lds DMA; one __syncthreads per K-tile (drains vmcnt).
template<int NT0, int NT, bool RELUOUT, bool OUTBF16>
__global__ __launch_bounds__(256)
void mfma_gemm(const ushort* __restrict__ A0, const ushort* __restrict__ A1,
               const ushort* __restrict__ WT, const float* __restrict__ bias,
               void* __restrict__ Cout, int M)
{
    __shared__ ushort As[2][128 * 64];
    __shared__ ushort Bs[2][128 * 64];
    const int tid  = threadIdx.x;
    const int bm   = blockIdx.x * 128;
    const int lane = tid & 63;
    const int w    = tid >> 6;
    const int wbase = w << 6;            // wave-uniform lane-0 slot
    const int wrow = (w >> 1) * 64;
    const int wcol = (w & 1) * 64;

    f32x4 acc[4][4];
    #pragma unroll
    for (int i = 0; i < 4; ++i)
        #pragma unroll
        for (int j = 0; j < 4; ++j)
            acc[i][j] = (f32x4){0.f, 0.f, 0.f, 0.f};

    // stage K-tile kt into buffer buf: 4 A-chunks + 4 B-chunks per thread, 16B DMA each.
    auto stage = [&](int kt, int buf) {
        #pragma unroll
        for (int st = 0; st < 4; ++st) {
            const int m = st * 256 + tid;      // 0..1023: (row, chunk-in-row)
            const int row = m >> 3;
            const int osrc = (m & 7) ^ (row & 7);   // pre-swizzled source octet
            int arow = bm + row; if (arow >= M) arow = M - 1;   // clamp: rows>=M unused
            const ushort* ga = (kt < NT0)
                ? A0 + (size_t)arow * (NT0 * 64) + kt * 64 + osrc * 8
                : A1 + (size_t)arow * ((NT - NT0) * 64) + (kt - NT0) * 64 + osrc * 8;
            gload16(ga, &As[buf][(st * 256 + wbase) * 8]);
            const ushort* gb = WT + (size_t)row * (NT * 64) + kt * 64 + osrc * 8;
            gload16(gb, &Bs[buf][(st * 256 + wbase) * 8]);
        }
    };

    stage(0, 0);
    __syncthreads();
    #pragma unroll
    for (int kt = 0; kt < NT; ++kt) {
        const int buf = kt & 1;
        if (kt + 1 < NT) stage(kt + 1, buf ^ 1);   // async DMA flies under MFMA below

        #pragma unroll
        for (int ks = 0; ks < 2; ++ks) {
            const int oq = ks * 4 + (lane >> 4);
            bf16x8 af[4], bfr[4];
            #pragma unroll
            for (int am = 0; am < 4; ++am) {
                const int row = wrow + am * 16 + (lane & 15);
                const int oL = oq ^ (row & 7);
                af[am] = *(const bf16x8*)&As[buf][row * 64 + oL * 8];
            }
            #pragma unroll
            for (int bn = 0; bn < 4; ++bn) {
                const int row = wcol + bn * 16 + (lane & 15);
                const int oL = oq ^ (row & 7);
                bfr[bn] = *(const bf16x8*)&Bs[buf][row * 64 + oL * 8];
            }
            #pragma unroll
            for (int am = 0; am < 4; ++am)
                #pragma unroll
                for (int bn = 0; bn < 4; ++bn)
                    acc[am][bn] = __builtin_amdgcn_mfma_f32_16x16x32_bf16(
                        af[am], bfr[bn], acc[am][bn], 0, 0, 0);
        }
        __syncthreads();   // drains DMA (vmcnt) + compute done before buffer reuse
    }

    // epilogue: row = bm+wrow+am*16+4*(lane>>4)+r ; col = wcol+bn*16+(lane&15)
    const int ccol = wcol + (lane & 15);
    float bb[4];
    #pragma unroll
    for (int bn = 0; bn < 4; ++bn) bb[bn] = bias[ccol + bn * 16];

    const int crow0 = bm + wrow + 4 * (lane >> 4);
    #pragma unroll
    for (int am = 0; am < 4; ++am) {
        #pragma unroll
        for (int r = 0; r < 4; ++r) {
            const int row = crow0 + am * 16 + r;
            if (row < M) {
                #pragma unroll
                for (int bn = 0; bn < 4; ++bn) {
                    float v = acc[am][bn][r] + bb[bn];
                    if (RELUOUT) v = fmaxf(v, 0.f);
                    if (OUTBF16)
                        ((ushort*)Cout)[(size_t)row * kD + ccol + bn * 16] = f2bf(v);
                    else
                        ((float*)Cout)[(size_t)row * kD + ccol + bn * 16] = v;
                }
            }
        }
    }
}

extern "C" void kernel_launch(void* const* d_in, const int* in_sizes, int n_in,
                              void* d_out, int out_size, void* d_ws, size_t ws_size,
                              hipStream_t stream)
{
    const float* x      = (const float*)d_in[0];
    const int*   esrc   = (const int*)d_in[1];
    const int*   edst   = (const int*)d_in[2];
    const float* proj_w = (const float*)d_in[3];
    const float* proj_b = (const float*)d_in[4];
    const float* basis1 = (const float*)d_in[5];
    const float* coeff1 = (const float*)d_in[6];
    const float* bias1  = (const float*)d_in[7];
    const float* loop1  = (const float*)d_in[8];
    const float* basis2 = (const float*)d_in[9];
    const float* coeff2 = (const float*)d_in[10];
    const float* bias2  = (const float*)d_in[11];
    const float* loop2  = (const float*)d_in[12];

    // ---- workspace layout ----
    char* p = (char*)d_ws;
    ushort* xb    = (ushort*)p;  p += (size_t)kN * kD * 2;        // bf16 x
    ushort* hb    = (ushort*)p;  p += (size_t)(kN + 1) * kD * 2;  // bf16 h (+ zero row kN)
    ushort* r1b   = (ushort*)p;  p += (size_t)(kN + 1) * kD * 2;  // bf16 relu(layer1) (+ zero row)
    ushort* ab    = (ushort*)p;  p += (size_t)kN * kKS * 2;       // bf16 gathered [N,384]
    ushort* WTp   = (ushort*)p;  p += (size_t)kD * kD * 2;        // proj_w^T
    ushort* WTc1  = (ushort*)p;  p += (size_t)kD * kKC * 2;       // [loop1 | Wstk1]^T
    ushort* WTc2  = (ushort*)p;  p += (size_t)kD * kKC * 2;       // [loop2 | Wstk2]^T
    float* invd   = (float*)p;   p += (size_t)kRN * 4;
    uint2* rowseg = (uint2*)p;   p += (size_t)kRN * 8;
    unsigned* bcur = (unsigned*)p;  p += (size_t)kNQ * 4;
    uint* colbkt   = (uint*)p;      p += (size_t)kNQ * kBCAP * 4;
    int* colidx    = (int*)p;       p += (size_t)kNQ * kICAP * 4;

    // ---- CSR build: fixed bucket slots, no global count/scan ----
    init_kernel<<<(kNQ + 255) / 256, 256, 0, stream>>>(bcur);
    passB_kernel<<<kCB, 256, 0, stream>>>(esrc, edst, bcur, colbkt);
    passC_kernel<<<kNQ, 256, 0, stream>>>(colbkt, bcur, rowseg, invd, colidx);

    // ---- fused weight prep + zero rows; x -> bf16 ----
    prep_kernel<<<578, 256, 0, stream>>>(proj_w, loop1, basis1, coeff1,
                                         loop2, basis2, coeff2, WTp, WTc1, WTc2,
                                         hb + (size_t)kN * kD, r1b + (size_t)kN * kD);
    f2bf_kernel<<<(kN * kD / 4) / 256, 256, 0, stream>>>(x, xb);

    const int gblocks = (kN + 127) / 128;   // 782
    const int gatherblocks = kRN / 32;      // 9375 exact

    // ---- projection: hb = bf16(x @ proj_w + proj_b) ----
    mfma_gemm<2, 2, false, true><<<gblocks, 256, 0, stream>>>(
        xb, nullptr, WTp, proj_b, hb, kN);

    // ---- layer 1: r1b = bf16(relu([h | gather(h)] @ [loop1|Wstk1] + bias1)) ----
    gather_kernel<<<gatherblocks, 256, 0, stream>>>(hb, rowseg, colidx, invd, ab);
    mfma_gemm<2, 8, true, true><<<gblocks, 256, 0, stream>>>(
        hb, ab, WTc1, bias1, r1b, kN);

    // ---- layer 2: out = relu([r1 | gather(r1)] @ [loop2|Wstk2] + bias2) (fp32) ----
    gather_kernel<<<gatherblocks, 256, 0, stream>>>(r1b, rowseg, colidx, invd, ab);
    mfma_gemm<2, 8, true, false><<<gblocks, 256, 0, stream>>>(
        r1b, ab, WTc2, bias2, d_out, kN);
}